// Round 4
// baseline (158.593 us; speedup 1.0000x reference)
//
#include <hip/hip_runtime.h>

typedef __attribute__((ext_vector_type(8))) __bf16 bf16x8;
typedef __attribute__((ext_vector_type(8))) unsigned short ushort8;
typedef __attribute__((ext_vector_type(4))) unsigned short ushort4v;
typedef __attribute__((ext_vector_type(4))) float f32x4;

namespace {
constexpr int kB = 8, kC = 128, kF = 256, kT = 128;

// ---- LDS map (ushort elements, 20480 total = 40 KB) ----
__device__ __forceinline__ int addrXT(int t, int p) { return t * 128 + (p ^ ((t & 7) << 3)); }
__device__ __forceinline__ int addrU(int ri, int e, int s) { return ri * 8192 + e * 128 + (s ^ ((e & 7) << 3)); }
__device__ __forceinline__ int addrK(int m, int c, int p) { return 16384 + m * 2048 + c * 32 + (p ^ ((c & 3) << 3)); }

__device__ __forceinline__ unsigned short b16(float f) {
    __bf16 h = (__bf16)f;
    return __builtin_bit_cast(unsigned short, h);
}

__device__ __forceinline__ bf16x8 ldfrag(const unsigned short* p, int idx) {
    return __builtin_bit_cast(bf16x8, *(const ushort8*)(p + idx));
}

__device__ __forceinline__ bf16x8 fneg(bf16x8 a) {
    ushort8 u = __builtin_bit_cast(ushort8, a);
    u ^= (unsigned short)0x8000;
    return __builtin_bit_cast(bf16x8, u);
}

// 8 consecutive fp32 from global -> bf16x8 fragment
__device__ __forceinline__ bf16x8 fragWg(const float* p) {
    f32x4 a = *(const f32x4*)p;
    f32x4 c = *(const f32x4*)(p + 4);
    bf16x8 r;
    r[0] = (__bf16)a[0]; r[1] = (__bf16)a[1]; r[2] = (__bf16)a[2]; r[3] = (__bf16)a[3];
    r[4] = (__bf16)c[0]; r[5] = (__bf16)c[1]; r[6] = (__bf16)c[2]; r[7] = (__bf16)c[3];
    return r;
}
} // namespace

// ---- weight pre-conversion: fp32 -> bf16 fragment-ready layout in d_ws ----
// ws frag id layout (each frag = 8 ushorts = one lane's A/B fragment):
//   [0,512)     Wk  : fid = ((tile*4+ks)*4+lg)*16+lr   (tile=dt 0..1)
//   [512,1024)  Wq  : same
//   [1024,3072) Wv  : fid-1024, tile=mt 0..7
__global__ __launch_bounds__(256)
void conv_weights(const float* __restrict__ Wk, const float* __restrict__ Wq,
                  const float* __restrict__ Wv, unsigned short* __restrict__ ws)
{
    const int fid = blockIdx.x * 256 + threadIdx.x;   // 0..3071
    if (fid >= 3072) return;
    const float* src;
    int local;
    if (fid < 512)       { src = Wk; local = fid; }
    else if (fid < 1024) { src = Wq; local = fid - 512; }
    else                 { src = Wv; local = fid - 1024; }
    const int lr = local & 15, lg = (local >> 4) & 3, ks = (local >> 6) & 3, tile = local >> 8;
    const float* p = src + (size_t)(16 * tile + lr) * kT + ks * 32 + 8 * lg;
    ushort8 o;
    #pragma unroll
    for (int j = 0; j < 8; ++j) o[j] = b16(p[j]);
    *(ushort8*)(ws + (size_t)fid * 8) = o;
}

__global__ __launch_bounds__(256, 4)
void chanattn_mfma3(const float* __restrict__ x,
                    const float* __restrict__ bk, const float* __restrict__ bq,
                    const float* __restrict__ bv,
                    const unsigned short* __restrict__ wsu,
                    float* __restrict__ out)
{
    __shared__ __align__(16) unsigned short lds[20480];

    const int f = blockIdx.x, b = blockIdx.y;
    const int tid = threadIdx.x;
    const int lane = tid & 63;
    const int w = tid >> 6;          // wave id 0..3
    const int lr = lane & 15;
    const int lg = lane >> 4;
    const size_t cstr = (size_t)kF * kT;
    const float* xb = x + ((size_t)b * kC * kF + f) * kT; // xb[c*cstr + t]

    // ============ Prefetch: phase-0 x tile into registers (issued FIRST) ============
    const int c0 = 4 * (tid & 31);           // channel quad 0..124
    const int t0 = 4 * (tid >> 5);           // 0..28
    f32x4 xv[4][4];
    #pragma unroll
    for (int tp = 0; tp < 4; ++tp)
        #pragma unroll
        for (int j = 0; j < 4; ++j)
            xv[tp][j] = *(const f32x4*)(xb + (size_t)(c0 + j) * cstr + t0 + 32 * tp);

    // ============ Phase A: per-wave K (-> LDS, permuted d) + Q (-> registers) ============
    bf16x8 bqr, bqi;
    {
        f32x4 qacc[2][2], kacc[2][2];   // [ri][dt]
        #pragma unroll
        for (int ri = 0; ri < 2; ++ri)
            #pragma unroll
            for (int dt = 0; dt < 2; ++dt) {
                qacc[ri][dt] = (f32x4){0.f, 0.f, 0.f, 0.f};
                kacc[ri][dt] = (f32x4){0.f, 0.f, 0.f, 0.f};
            }
        #pragma unroll
        for (int ks = 0; ks < 4; ++ks) {
            bf16x8 xr_f = fragWg(xb + (size_t)(16 * w + lr) * cstr + ks * 32 + 8 * lg);
            bf16x8 xi_f = fragWg(xb + (size_t)(64 + 16 * w + lr) * cstr + ks * 32 + 8 * lg);
            #pragma unroll
            for (int dt = 0; dt < 2; ++dt) {
                bf16x8 wk = ldfrag(wsu, (((dt * 4 + ks) * 4 + lg) * 16 + lr) * 8);
                bf16x8 wq = ldfrag(wsu, 4096 + (((dt * 4 + ks) * 4 + lg) * 16 + lr) * 8);
                qacc[0][dt] = __builtin_amdgcn_mfma_f32_16x16x32_bf16(wq, xr_f, qacc[0][dt], 0, 0, 0);
                qacc[1][dt] = __builtin_amdgcn_mfma_f32_16x16x32_bf16(wq, xi_f, qacc[1][dt], 0, 0, 0);
                kacc[0][dt] = __builtin_amdgcn_mfma_f32_16x16x32_bf16(xr_f, wk, kacc[0][dt], 0, 0, 0);
                kacc[1][dt] = __builtin_amdgcn_mfma_f32_16x16x32_bf16(xi_f, wk, kacc[1][dt], 0, 0, 0);
            }
        }
        // K -> LDS: value for d=16*dt+lr stored at position p = 8*((lr>>2)&3) + 4*dt + (lr&3)
        const float bk0 = bk[lr], bk1 = bk[16 + lr];
        #pragma unroll
        for (int dt = 0; dt < 2; ++dt) {
            const int pcol = 8 * ((lr >> 2) & 3) + 4 * dt + (lr & 3);
            const float bb = dt ? bk1 : bk0;
            #pragma unroll
            for (int r = 0; r < 4; ++r) {
                const int c = 16 * w + 4 * lg + r;
                lds[addrK(0, c, pcol)] = b16(kacc[0][dt][r] + bb);
                lds[addrK(1, c, pcol)] = b16(kacc[1][dt][r] + bb);
            }
        }
        // Q -> B-frags in-register: element j <- slot(dt=j>>2, r=j&3)
        #pragma unroll
        for (int j = 0; j < 8; ++j) {
            const int dt = j >> 2, r = j & 3;
            const float bb = bq[16 * dt + 4 * lg + r];
            bqr[j] = (__bf16)(qacc[0][dt][r] + bb);
            bqi[j] = (__bf16)(qacc[1][dt][r] + bb);
        }
    }

    // ============ Phase 0 (write side): prefetched x -> XT[t][p] ============
    {
        const int h  = c0 >> 6;
        const int cc = c0 & 63;
        const int p0 = 64 * h + 32 * (cc >> 5) + 8 * ((cc >> 2) & 3) + 4 * ((cc >> 4) & 1);
        #pragma unroll
        for (int tp = 0; tp < 4; ++tp) {
            const int t = t0 + 32 * tp;
            #pragma unroll
            for (int i = 0; i < 4; ++i) {
                ushort4v pk;
                pk[0] = b16(xv[tp][0][i]); pk[1] = b16(xv[tp][1][i]);
                pk[2] = b16(xv[tp][2][i]); pk[3] = b16(xv[tp][3][i]);
                *(ushort4v*)&lds[addrXT(t + i, p0)] = pk;
            }
        }
    }
    __syncthreads();   // barrier 1: XT + K ready

    // ============ Phase B: P = K^T Q (complex), softmax over c ============
    f32x4 pr[4], pi[4];
    float inv_r, inv_i;
    {
        const f32x4 zero = {0.f, 0.f, 0.f, 0.f};
        #pragma unroll
        for (int ct = 0; ct < 4; ++ct) {
            bf16x8 akr = ldfrag(lds, addrK(0, ct * 16 + lr, 8 * lg));
            bf16x8 aki = ldfrag(lds, addrK(1, ct * 16 + lr, 8 * lg));
            pr[ct] = __builtin_amdgcn_mfma_f32_16x16x32_bf16(akr, bqr, zero, 0, 0, 0);
            pr[ct] = __builtin_amdgcn_mfma_f32_16x16x32_bf16(fneg(aki), bqi, pr[ct], 0, 0, 0);
            pi[ct] = __builtin_amdgcn_mfma_f32_16x16x32_bf16(akr, bqi, zero, 0, 0, 0);
            pi[ct] = __builtin_amdgcn_mfma_f32_16x16x32_bf16(aki, bqr, pi[ct], 0, 0, 0);
        }
        float mr = -1e30f, mi = -1e30f;
        #pragma unroll
        for (int ct = 0; ct < 4; ++ct)
            #pragma unroll
            for (int r = 0; r < 4; ++r) { mr = fmaxf(mr, pr[ct][r]); mi = fmaxf(mi, pi[ct][r]); }
        mr = fmaxf(mr, __shfl_xor(mr, 16)); mr = fmaxf(mr, __shfl_xor(mr, 32));
        mi = fmaxf(mi, __shfl_xor(mi, 16)); mi = fmaxf(mi, __shfl_xor(mi, 32));
        float sr = 0.f, si = 0.f;
        #pragma unroll
        for (int ct = 0; ct < 4; ++ct)
            #pragma unroll
            for (int r = 0; r < 4; ++r) {
                float er = __expf(pr[ct][r] - mr); pr[ct][r] = er; sr += er;
                float ei = __expf(pi[ct][r] - mi); pi[ct][r] = ei; si += ei;
            }
        sr += __shfl_xor(sr, 16); sr += __shfl_xor(sr, 32);
        si += __shfl_xor(si, 16); si += __shfl_xor(si, 32);
        inv_r = 1.f / sr; inv_i = 1.f / si;
    }

    // W A-frags in-register: element (ks, j) <- slot(ct = 2*ks + (j>>2), r = j&3)
    bf16x8 awr[2], awi[2], awin[2];
    #pragma unroll
    for (int ks = 0; ks < 2; ++ks) {
        #pragma unroll
        for (int j = 0; j < 8; ++j) {
            const int ct = 2 * ks + (j >> 2), r = j & 3;
            awr[ks][j] = (__bf16)(pr[ct][r] * inv_r);
            awi[ks][j] = (__bf16)(pi[ct][r] * inv_i);
        }
        awin[ks] = fneg(awi[ks]);
    }

    // ============ Phase C: U[e][t] = sum_c W[c][e] X[c][t] (complex) ============
    f32x4 uacc_r[8], uacc_i[8];
    #pragma unroll
    for (int nt = 0; nt < 8; ++nt) {
        f32x4 ur = {0.f, 0.f, 0.f, 0.f}, ui = {0.f, 0.f, 0.f, 0.f};
        #pragma unroll
        for (int ks = 0; ks < 2; ++ks) {
            bf16x8 bxr = ldfrag(lds, addrXT(nt * 16 + lr, ks * 32 + 8 * lg));
            bf16x8 bxi = ldfrag(lds, addrXT(nt * 16 + lr, 64 + ks * 32 + 8 * lg));
            ur = __builtin_amdgcn_mfma_f32_16x16x32_bf16(awr[ks], bxr, ur, 0, 0, 0);
            ur = __builtin_amdgcn_mfma_f32_16x16x32_bf16(awin[ks], bxi, ur, 0, 0, 0);
            ui = __builtin_amdgcn_mfma_f32_16x16x32_bf16(awi[ks], bxr, ui, 0, 0, 0);
            ui = __builtin_amdgcn_mfma_f32_16x16x32_bf16(awr[ks], bxi, ui, 0, 0, 0);
        }
        uacc_r[nt] = ur; uacc_i[nt] = ui;
    }

    // Prefetch phase-D weights (bf16 frags from ws) before the barriers
    bf16x8 av[2][4];
    float bvv[2][4];
    #pragma unroll
    for (int mi_ = 0; mi_ < 2; ++mi_) {
        const int mt = 2 * w + mi_;
        #pragma unroll
        for (int ks = 0; ks < 4; ++ks)
            av[mi_][ks] = ldfrag(wsu, 8192 + (((mt * 4 + ks) * 4 + lg) * 16 + lr) * 8);
        #pragma unroll
        for (int r = 0; r < 4; ++r) bvv[mi_][r] = 2.f * bv[mt * 16 + 4 * lg + r];
    }

    __syncthreads();   // barrier 2: all waves done reading XT
    #pragma unroll
    for (int nt = 0; nt < 8; ++nt)
        #pragma unroll
        for (int r = 0; r < 4; ++r) {
            const int e = 16 * w + 4 * lg + r;
            lds[addrU(0, e, nt * 16 + lr)] = b16(uacc_r[nt][r]);
            lds[addrU(1, e, nt * 16 + lr)] = b16(uacc_i[nt][r]);
        }
    __syncthreads();   // barrier 3: UT ready

    // ============ Phase D: O[t'][e] = Wv * U (+2bv on imag), store fp32 ============
    {
        #pragma unroll
        for (int mi_ = 0; mi_ < 2; ++mi_) {
            const int mt = 2 * w + mi_;      // t'-tile 0..7
            #pragma unroll
            for (int et = 0; et < 4; ++et) {
                f32x4 aor = {0.f, 0.f, 0.f, 0.f}, aoi = {0.f, 0.f, 0.f, 0.f};
                #pragma unroll
                for (int ks = 0; ks < 4; ++ks) {
                    bf16x8 bur = ldfrag(lds, addrU(0, et * 16 + lr, ks * 32 + 8 * lg));
                    bf16x8 bui = ldfrag(lds, addrU(1, et * 16 + lr, ks * 32 + 8 * lg));
                    aor = __builtin_amdgcn_mfma_f32_16x16x32_bf16(av[mi_][ks], bur, aor, 0, 0, 0);
                    aoi = __builtin_amdgcn_mfma_f32_16x16x32_bf16(av[mi_][ks], bui, aoi, 0, 0, 0);
                }
                const int e = et * 16 + lr;
                const int tp0 = mt * 16 + 4 * lg;
                f32x4 vi;
                #pragma unroll
                for (int r = 0; r < 4; ++r) vi[r] = aoi[r] + bvv[mi_][r];
                *(f32x4*)(out + (((size_t)b * kC + e) * kF + f) * kT + tp0)      = aor;
                *(f32x4*)(out + (((size_t)b * kC + 64 + e) * kF + f) * kT + tp0) = vi;
            }
        }
    }
}

extern "C" void kernel_launch(void* const* d_in, const int* in_sizes, int n_in,
                              void* d_out, int out_size, void* d_ws, size_t ws_size,
                              hipStream_t stream) {
    const float* x  = (const float*)d_in[0];
    const float* Wk = (const float*)d_in[1];
    const float* bk = (const float*)d_in[2];
    const float* Wq = (const float*)d_in[3];
    const float* bq = (const float*)d_in[4];
    const float* Wv = (const float*)d_in[5];
    const float* bv = (const float*)d_in[6];
    float* out = (float*)d_out;
    unsigned short* wsu = (unsigned short*)d_ws;

    // 1) weights -> bf16 fragment layout in workspace (3072 frags)
    conv_weights<<<dim3(12), dim3(256), 0, stream>>>(Wk, Wq, Wv, wsu);

    // 2) main fused kernel, one block per (b, f)
    dim3 grid(kF, kB);
    dim3 block(256);
    chanattn_mfma3<<<grid, block, 0, stream>>>(x, bk, bq, bv, wsu, out);
}

// Round 5
// 146.989 us; speedup vs baseline: 1.0789x; 1.0789x over previous
//
#include <hip/hip_runtime.h>

typedef __attribute__((ext_vector_type(8))) __bf16 bf16x8;
typedef __attribute__((ext_vector_type(8))) unsigned short ushort8;
typedef __attribute__((ext_vector_type(4))) unsigned short ushort4v;
typedef __attribute__((ext_vector_type(4))) float f32x4;

namespace {
constexpr int kB = 8, kC = 128, kF = 256, kT = 128;

// ---- LDS map (ushort elements, 20480 total = 40 KB) ----
// [0, 16384)      : XT[t=128][p=128]  (tau-permuted channel axis, XOR-swizzled)
//                   After barrier 2, aliased per-wave by U: wave w owns [w*4096, w*4096+4096)
// [16384, 20480)  : K[mat=2][c=64][p=32] (delta-permuted d axis)
__device__ __forceinline__ int addrXT(int t, int p) { return t * 128 + (p ^ ((t & 7) << 3)); }
__device__ __forceinline__ int addrK(int m, int c, int p) { return 16384 + m * 2048 + c * 32 + (p ^ ((c & 3) << 3)); }
// wave-private U: e' = 0..15 (col lane), s = 0..127
__device__ __forceinline__ int addrUw(int w, int ri, int ep, int s) {
    return w * 4096 + ri * 2048 + ep * 128 + (s ^ ((ep & 7) << 3));
}

__device__ __forceinline__ unsigned short b16(float f) {
    __bf16 h = (__bf16)f;
    return __builtin_bit_cast(unsigned short, h);
}

__device__ __forceinline__ bf16x8 ldfrag(const unsigned short* p, int idx) {
    return __builtin_bit_cast(bf16x8, *(const ushort8*)(p + idx));
}

__device__ __forceinline__ bf16x8 fneg(bf16x8 a) {
    ushort8 u = __builtin_bit_cast(ushort8, a);
    u ^= (unsigned short)0x8000;
    return __builtin_bit_cast(bf16x8, u);
}

// 8 consecutive fp32 from global -> bf16x8 fragment
__device__ __forceinline__ bf16x8 fragWg(const float* p) {
    f32x4 a = *(const f32x4*)p;
    f32x4 c = *(const f32x4*)(p + 4);
    bf16x8 r;
    r[0] = (__bf16)a[0]; r[1] = (__bf16)a[1]; r[2] = (__bf16)a[2]; r[3] = (__bf16)a[3];
    r[4] = (__bf16)c[0]; r[5] = (__bf16)c[1]; r[6] = (__bf16)c[2]; r[7] = (__bf16)c[3];
    return r;
}
} // namespace

__global__ __launch_bounds__(256, 4)
void chanattn_mfma4(const float* __restrict__ x,
                    const float* __restrict__ Wk, const float* __restrict__ bk,
                    const float* __restrict__ Wq, const float* __restrict__ bq,
                    const float* __restrict__ Wv, const float* __restrict__ bv,
                    float* __restrict__ out)
{
    __shared__ __align__(16) unsigned short lds[20480];

    const int f = blockIdx.x, b = blockIdx.y;
    const int tid = threadIdx.x;
    const int lane = tid & 63;
    const int w = tid >> 6;          // wave id 0..3
    const int lr = lane & 15;
    const int lg = lane >> 4;
    const size_t cstr = (size_t)kF * kT;
    const float* xb = x + ((size_t)b * kC * kF + f) * kT; // xb[c*cstr + t]

    // ============ Phase 0 FIRST: x -> XT[t][p] (bf16, tau-permuted, swizzled) ============
    // Streams the whole 64KB x-tile through L2 so phase A's re-reads are L2 hits.
    {
        const int c0 = 4 * (tid & 31);           // channel quad 0..124
        const int t0 = 4 * (tid >> 5);           // 0..28
        const int h  = c0 >> 6;
        const int cc = c0 & 63;
        const int p0 = 64 * h + 32 * (cc >> 5) + 8 * ((cc >> 2) & 3) + 4 * ((cc >> 4) & 1);
        f32x4 xv[4][4];
        #pragma unroll
        for (int tp = 0; tp < 4; ++tp)
            #pragma unroll
            for (int j = 0; j < 4; ++j)
                xv[tp][j] = *(const f32x4*)(xb + (size_t)(c0 + j) * cstr + t0 + 32 * tp);
        #pragma unroll
        for (int tp = 0; tp < 4; ++tp) {
            const int t = t0 + 32 * tp;
            #pragma unroll
            for (int i = 0; i < 4; ++i) {
                ushort4v pk;
                pk[0] = b16(xv[tp][0][i]); pk[1] = b16(xv[tp][1][i]);
                pk[2] = b16(xv[tp][2][i]); pk[3] = b16(xv[tp][3][i]);
                *(ushort4v*)&lds[addrXT(t + i, p0)] = pk;
            }
        }
    }

    // ============ Phase A: per-wave K (-> LDS, permuted d) + Q (-> registers) ============
    bf16x8 bqr, bqi;
    {
        bf16x8 xr_f[4], xi_f[4];
        #pragma unroll
        for (int ks = 0; ks < 4; ++ks) {
            xr_f[ks] = fragWg(xb + (size_t)(16 * w + lr) * cstr + ks * 32 + 8 * lg);
            xi_f[ks] = fragWg(xb + (size_t)(64 + 16 * w + lr) * cstr + ks * 32 + 8 * lg);
        }
        f32x4 qacc[2][2], kacc[2][2];   // [ri][dt]
        #pragma unroll
        for (int ri = 0; ri < 2; ++ri)
            #pragma unroll
            for (int dt = 0; dt < 2; ++dt) {
                qacc[ri][dt] = (f32x4){0.f, 0.f, 0.f, 0.f};
                kacc[ri][dt] = (f32x4){0.f, 0.f, 0.f, 0.f};
            }
        #pragma unroll
        for (int dt = 0; dt < 2; ++dt)
            #pragma unroll
            for (int ks = 0; ks < 4; ++ks) {
                bf16x8 wq = fragWg(Wq + (size_t)(16 * dt + lr) * kT + ks * 32 + 8 * lg);
                bf16x8 wk = fragWg(Wk + (size_t)(16 * dt + lr) * kT + ks * 32 + 8 * lg);
                qacc[0][dt] = __builtin_amdgcn_mfma_f32_16x16x32_bf16(wq, xr_f[ks], qacc[0][dt], 0, 0, 0);
                qacc[1][dt] = __builtin_amdgcn_mfma_f32_16x16x32_bf16(wq, xi_f[ks], qacc[1][dt], 0, 0, 0);
                kacc[0][dt] = __builtin_amdgcn_mfma_f32_16x16x32_bf16(xr_f[ks], wk, kacc[0][dt], 0, 0, 0);
                kacc[1][dt] = __builtin_amdgcn_mfma_f32_16x16x32_bf16(xi_f[ks], wk, kacc[1][dt], 0, 0, 0);
            }
        // K -> LDS: value for d=16*dt+lr stored at position p = 8*((lr>>2)&3) + 4*dt + (lr&3)
        const float bk0 = bk[lr], bk1 = bk[16 + lr];
        #pragma unroll
        for (int dt = 0; dt < 2; ++dt) {
            const int pcol = 8 * ((lr >> 2) & 3) + 4 * dt + (lr & 3);
            const float bb = dt ? bk1 : bk0;
            #pragma unroll
            for (int r = 0; r < 4; ++r) {
                const int c = 16 * w + 4 * lg + r;
                lds[addrK(0, c, pcol)] = b16(kacc[0][dt][r] + bb);
                lds[addrK(1, c, pcol)] = b16(kacc[1][dt][r] + bb);
            }
        }
        // Q -> B-frags in-register: element j <- slot(dt=j>>2, r=j&3)
        #pragma unroll
        for (int j = 0; j < 8; ++j) {
            const int dt = j >> 2, r = j & 3;
            const float bb = bq[16 * dt + 4 * lg + r];
            bqr[j] = (__bf16)(qacc[0][dt][r] + bb);
            bqi[j] = (__bf16)(qacc[1][dt][r] + bb);
        }
    }
    __syncthreads();   // barrier 1: XT + K ready

    // ============ Phase B: P = K^T Q (complex), softmax over c ============
    f32x4 pr[4], pi[4];
    float inv_r, inv_i;
    {
        const f32x4 zero = {0.f, 0.f, 0.f, 0.f};
        #pragma unroll
        for (int ct = 0; ct < 4; ++ct) {
            bf16x8 akr = ldfrag(lds, addrK(0, ct * 16 + lr, 8 * lg));
            bf16x8 aki = ldfrag(lds, addrK(1, ct * 16 + lr, 8 * lg));
            pr[ct] = __builtin_amdgcn_mfma_f32_16x16x32_bf16(akr, bqr, zero, 0, 0, 0);
            pr[ct] = __builtin_amdgcn_mfma_f32_16x16x32_bf16(fneg(aki), bqi, pr[ct], 0, 0, 0);
            pi[ct] = __builtin_amdgcn_mfma_f32_16x16x32_bf16(akr, bqi, zero, 0, 0, 0);
            pi[ct] = __builtin_amdgcn_mfma_f32_16x16x32_bf16(aki, bqr, pi[ct], 0, 0, 0);
        }
        float mr = -1e30f, mi = -1e30f;
        #pragma unroll
        for (int ct = 0; ct < 4; ++ct)
            #pragma unroll
            for (int r = 0; r < 4; ++r) { mr = fmaxf(mr, pr[ct][r]); mi = fmaxf(mi, pi[ct][r]); }
        mr = fmaxf(mr, __shfl_xor(mr, 16)); mr = fmaxf(mr, __shfl_xor(mr, 32));
        mi = fmaxf(mi, __shfl_xor(mi, 16)); mi = fmaxf(mi, __shfl_xor(mi, 32));
        float sr = 0.f, si = 0.f;
        #pragma unroll
        for (int ct = 0; ct < 4; ++ct)
            #pragma unroll
            for (int r = 0; r < 4; ++r) {
                float er = __expf(pr[ct][r] - mr); pr[ct][r] = er; sr += er;
                float ei = __expf(pi[ct][r] - mi); pi[ct][r] = ei; si += ei;
            }
        sr += __shfl_xor(sr, 16); sr += __shfl_xor(sr, 32);
        si += __shfl_xor(si, 16); si += __shfl_xor(si, 32);
        inv_r = 1.f / sr; inv_i = 1.f / si;
    }

    // W frags in-register (lane lr <-> e = 16w+lr): element (ks, j) <- slot(ct = 2*ks + (j>>2), r = j&3)
    bf16x8 awr[2], awi[2], awin[2];
    #pragma unroll
    for (int ks = 0; ks < 2; ++ks) {
        #pragma unroll
        for (int j = 0; j < 8; ++j) {
            const int ct = 2 * ks + (j >> 2), r = j & 3;
            awr[ks][j] = (__bf16)(pr[ct][r] * inv_r);
            awi[ks][j] = (__bf16)(pi[ct][r] * inv_i);
        }
        awin[ks] = fneg(awi[ks]);
    }

    // ============ Phase C' (operand-swapped): U'[t][e] = sum_c X^T[t][c] W[c][e] ============
    // A = XT fragments (row = t), B = W fragments (col = e, wave-local 16 e's).
    // Output: lane holds U[s = nt*16 + 4*lg + r][e' = lr] -> wave owns its full 16-e U slice.
    f32x4 uacc_r[8], uacc_i[8];
    #pragma unroll
    for (int nt = 0; nt < 8; ++nt) {
        f32x4 ur = {0.f, 0.f, 0.f, 0.f}, ui = {0.f, 0.f, 0.f, 0.f};
        #pragma unroll
        for (int ks = 0; ks < 2; ++ks) {
            bf16x8 bxr = ldfrag(lds, addrXT(nt * 16 + lr, ks * 32 + 8 * lg));
            bf16x8 bxi = ldfrag(lds, addrXT(nt * 16 + lr, 64 + ks * 32 + 8 * lg));
            ur = __builtin_amdgcn_mfma_f32_16x16x32_bf16(bxr, awr[ks], ur, 0, 0, 0);
            ur = __builtin_amdgcn_mfma_f32_16x16x32_bf16(bxi, awin[ks], ur, 0, 0, 0);
            ui = __builtin_amdgcn_mfma_f32_16x16x32_bf16(bxr, awi[ks], ui, 0, 0, 0);
            ui = __builtin_amdgcn_mfma_f32_16x16x32_bf16(bxi, awr[ks], ui, 0, 0, 0);
        }
        uacc_r[nt] = ur; uacc_i[nt] = ui;
    }
    __syncthreads();   // barrier 2: all waves done reading XT (and K is dead) -> alias with U

    // ============ U -> wave-private LDS (no further barriers; waves desync from here) ======
    #pragma unroll
    for (int nt = 0; nt < 8; ++nt) {
        ushort4v qr_, qi_;
        #pragma unroll
        for (int r = 0; r < 4; ++r) { qr_[r] = b16(uacc_r[nt][r]); qi_[r] = b16(uacc_i[nt][r]); }
        const int s = nt * 16 + 4 * lg;
        *(ushort4v*)&lds[addrUw(w, 0, lr, s)] = qr_;
        *(ushort4v*)&lds[addrUw(w, 1, lr, s)] = qi_;
    }
    asm volatile("s_waitcnt lgkmcnt(0)" ::: "memory");   // wave-local RAW on LDS

    // ============ Phase D' (swapped): O[t'][e] = sum_s Wv[t'][s] U[e][s] ============
    // A = Wv fragments (row = t'), B = own-U fragments (col = e' = lr).
    #pragma unroll
    for (int mt = 0; mt < 8; ++mt) {
        bf16x8 av[4];
        #pragma unroll
        for (int ks = 0; ks < 4; ++ks)
            av[ks] = fragWg(Wv + (size_t)(16 * mt + lr) * kT + ks * 32 + 8 * lg);
        f32x4 aor = {0.f, 0.f, 0.f, 0.f}, aoi = {0.f, 0.f, 0.f, 0.f};
        #pragma unroll
        for (int ks = 0; ks < 4; ++ks) {
            bf16x8 bur = ldfrag(lds, addrUw(w, 0, lr, ks * 32 + 8 * lg));
            bf16x8 bui = ldfrag(lds, addrUw(w, 1, lr, ks * 32 + 8 * lg));
            aor = __builtin_amdgcn_mfma_f32_16x16x32_bf16(av[ks], bur, aor, 0, 0, 0);
            aoi = __builtin_amdgcn_mfma_f32_16x16x32_bf16(av[ks], bui, aoi, 0, 0, 0);
        }
        // lane output: e = 16w+lr; t' = mt*16 + 4*lg + r (4 consecutive -> f32x4)
        const int e   = 16 * w + lr;
        const int tp0 = mt * 16 + 4 * lg;
        f32x4 vi;
        #pragma unroll
        for (int r = 0; r < 4; ++r) vi[r] = aoi[r] + 2.f * bv[tp0 + r];
        *(f32x4*)(out + (((size_t)b * kC + e) * kF + f) * kT + tp0)      = aor;
        *(f32x4*)(out + (((size_t)b * kC + 64 + e) * kF + f) * kT + tp0) = vi;
    }
}

extern "C" void kernel_launch(void* const* d_in, const int* in_sizes, int n_in,
                              void* d_out, int out_size, void* d_ws, size_t ws_size,
                              hipStream_t stream) {
    const float* x  = (const float*)d_in[0];
    const float* Wk = (const float*)d_in[1];
    const float* bk = (const float*)d_in[2];
    const float* Wq = (const float*)d_in[3];
    const float* bq = (const float*)d_in[4];
    const float* Wv = (const float*)d_in[5];
    const float* bv = (const float*)d_in[6];
    float* out = (float*)d_out;

    dim3 grid(kF, kB);   // one block per (b, f)
    dim3 block(256);
    chanattn_mfma4<<<grid, block, 0, stream>>>(x, Wk, bk, Wq, bq, Wv, bv, out);
}

// Round 6
// 115.765 us; speedup vs baseline: 1.3700x; 1.2697x over previous
//
#include <hip/hip_runtime.h>

typedef __attribute__((ext_vector_type(8))) __bf16 bf16x8;
typedef __attribute__((ext_vector_type(8))) unsigned short ushort8;
typedef __attribute__((ext_vector_type(4))) unsigned short ushort4v;
typedef __attribute__((ext_vector_type(4))) float f32x4;

namespace {
constexpr int kB = 8, kC = 128, kF = 256, kT = 128;

// ---- LDS map (ushort elements, 24576 total = 48 KB) ----
// [0, 16384)      : XT[t=128][p=128] (tau-permuted channel axis, XOR-swizzled).
//                   After barrier 2, aliased by UT[ri][e][s] (R2 layout).
// [16384, 20480)  : K[mat=2][c=64][p=32] (delta-permuted d axis)
// [20480, 24576)  : Q[mat=2][e=64][p=32] (delta-permuted d axis)
__device__ __forceinline__ int addrXT(int t, int p) { return t * 128 + (p ^ ((t & 7) << 3)); }
__device__ __forceinline__ int addrU(int ri, int e, int s) { return ri * 8192 + e * 128 + (s ^ ((e & 7) << 3)); }
__device__ __forceinline__ int addrK(int m, int c, int p) { return 16384 + m * 2048 + c * 32 + (p ^ ((c & 3) << 3)); }
__device__ __forceinline__ int addrQ(int m, int e, int p) { return 20480 + m * 2048 + e * 32 + (p ^ ((e & 3) << 3)); }

__device__ __forceinline__ unsigned short b16(float f) {
    __bf16 h = (__bf16)f;
    return __builtin_bit_cast(unsigned short, h);
}

__device__ __forceinline__ bf16x8 ldfrag(const unsigned short* p, int idx) {
    return __builtin_bit_cast(bf16x8, *(const ushort8*)(p + idx));
}

__device__ __forceinline__ bf16x8 fneg(bf16x8 a) {
    ushort8 u = __builtin_bit_cast(ushort8, a);
    u ^= (unsigned short)0x8000;
    return __builtin_bit_cast(bf16x8, u);
}

// 8 consecutive fp32 from global -> bf16x8 fragment
__device__ __forceinline__ bf16x8 fragWg(const float* p) {
    f32x4 a = *(const f32x4*)p;
    f32x4 c = *(const f32x4*)(p + 4);
    bf16x8 r;
    r[0] = (__bf16)a[0]; r[1] = (__bf16)a[1]; r[2] = (__bf16)a[2]; r[3] = (__bf16)a[3];
    r[4] = (__bf16)c[0]; r[5] = (__bf16)c[1]; r[6] = (__bf16)c[2]; r[7] = (__bf16)c[3];
    return r;
}
} // namespace

__global__ __launch_bounds__(512, 4)
void chanattn_mfma5(const float* __restrict__ x,
                    const float* __restrict__ Wk, const float* __restrict__ bk,
                    const float* __restrict__ Wq, const float* __restrict__ bq,
                    const float* __restrict__ Wv, const float* __restrict__ bv,
                    float* __restrict__ out)
{
    __shared__ __align__(16) unsigned short lds[24576];

    const int f = blockIdx.x, b = blockIdx.y;
    const int tid = threadIdx.x;
    const int lane = tid & 63;
    const int w = tid >> 6;          // wave id 0..7
    const int wt = w & 3;            // e-tile / c-tile index
    const int lr = lane & 15;
    const int lg = lane >> 4;
    const size_t cstr = (size_t)kF * kT;
    const float* xb = x + ((size_t)b * kC * kF + f) * kT; // xb[c*cstr + t]

    // ============ Phase A: waves 0-3 K-proj -> LDS; waves 4-7 Q-proj -> LDS ============
    {
        // x fragments for this wave's 16-row c/e tile (r and i halves)
        bf16x8 xr_f[4], xi_f[4];
        #pragma unroll
        for (int ks = 0; ks < 4; ++ks) {
            xr_f[ks] = fragWg(xb + (size_t)(16 * wt + lr) * cstr + ks * 32 + 8 * lg);
            xi_f[ks] = fragWg(xb + (size_t)(64 + 16 * wt + lr) * cstr + ks * 32 + 8 * lg);
        }
        if (w < 4) {
            // K: kacc[ri][dt] = mfma(x, Wk) -> lane holds (row c = 16wt+4lg+r, col d = 16dt+lr)
            f32x4 kacc[2][2];
            #pragma unroll
            for (int ri = 0; ri < 2; ++ri)
                #pragma unroll
                for (int dt = 0; dt < 2; ++dt) kacc[ri][dt] = (f32x4){0.f, 0.f, 0.f, 0.f};
            #pragma unroll
            for (int dt = 0; dt < 2; ++dt)
                #pragma unroll
                for (int ks = 0; ks < 4; ++ks) {
                    bf16x8 wk = fragWg(Wk + (size_t)(16 * dt + lr) * kT + ks * 32 + 8 * lg);
                    kacc[0][dt] = __builtin_amdgcn_mfma_f32_16x16x32_bf16(xr_f[ks], wk, kacc[0][dt], 0, 0, 0);
                    kacc[1][dt] = __builtin_amdgcn_mfma_f32_16x16x32_bf16(xi_f[ks], wk, kacc[1][dt], 0, 0, 0);
                }
            const float bk0 = bk[lr], bk1 = bk[16 + lr];
            #pragma unroll
            for (int dt = 0; dt < 2; ++dt) {
                const int pcol = 8 * ((lr >> 2) & 3) + 4 * dt + (lr & 3);
                const float bb = dt ? bk1 : bk0;
                #pragma unroll
                for (int r = 0; r < 4; ++r) {
                    const int c = 16 * wt + 4 * lg + r;
                    lds[addrK(0, c, pcol)] = b16(kacc[0][dt][r] + bb);
                    lds[addrK(1, c, pcol)] = b16(kacc[1][dt][r] + bb);
                }
            }
        } else {
            // Q: qacc[ri][dt] = mfma(Wq, x) -> lane holds (row d = 16dt+4lg+r, col e = 16wt+lr)
            f32x4 qacc[2][2];
            #pragma unroll
            for (int ri = 0; ri < 2; ++ri)
                #pragma unroll
                for (int dt = 0; dt < 2; ++dt) qacc[ri][dt] = (f32x4){0.f, 0.f, 0.f, 0.f};
            #pragma unroll
            for (int dt = 0; dt < 2; ++dt)
                #pragma unroll
                for (int ks = 0; ks < 4; ++ks) {
                    bf16x8 wq = fragWg(Wq + (size_t)(16 * dt + lr) * kT + ks * 32 + 8 * lg);
                    qacc[0][dt] = __builtin_amdgcn_mfma_f32_16x16x32_bf16(wq, xr_f[ks], qacc[0][dt], 0, 0, 0);
                    qacc[1][dt] = __builtin_amdgcn_mfma_f32_16x16x32_bf16(wq, xi_f[ks], qacc[1][dt], 0, 0, 0);
                }
            // store at p = 8*lg + 4*dt + r  (delta permutation of d = 16dt+4lg+r)
            const int e = 16 * wt + lr;
            #pragma unroll
            for (int dt = 0; dt < 2; ++dt)
                #pragma unroll
                for (int r = 0; r < 4; ++r) {
                    const float bb = bq[16 * dt + 4 * lg + r];
                    const int p = 8 * lg + 4 * dt + r;
                    lds[addrQ(0, e, p)] = b16(qacc[0][dt][r] + bb);
                    lds[addrQ(1, e, p)] = b16(qacc[1][dt][r] + bb);
                }
        }
    }

    // ============ Phase 0: x -> XT[t][p] (bf16, tau-permuted, swizzled), 512 threads ======
    {
        const int c0 = 4 * (tid & 31);           // channel quad 0..124
        const int t0 = 4 * (tid >> 5);           // 0..60 (16 slots)
        const int h  = c0 >> 6;
        const int cc = c0 & 63;
        const int p0 = 64 * h + 32 * (cc >> 5) + 8 * ((cc >> 2) & 3) + 4 * ((cc >> 4) & 1);
        #pragma unroll
        for (int tp = 0; tp < 2; ++tp) {
            const int t = t0 + 64 * tp;
            f32x4 v[4];
            #pragma unroll
            for (int j = 0; j < 4; ++j)
                v[j] = *(const f32x4*)(xb + (size_t)(c0 + j) * cstr + t);
            #pragma unroll
            for (int i = 0; i < 4; ++i) {
                ushort4v pk;
                pk[0] = b16(v[0][i]); pk[1] = b16(v[1][i]);
                pk[2] = b16(v[2][i]); pk[3] = b16(v[3][i]);
                *(ushort4v*)&lds[addrXT(t + i, p0)] = pk;
            }
        }
    }
    __syncthreads();   // barrier 1: XT + K + Q ready

    // ============ Phase B: P = K^T Q (complex) + softmax (pairs w, w+4 duplicate e-tile wt) ==
    f32x4 pr[4], pi[4];
    float inv_r, inv_i;
    {
        const f32x4 zero = {0.f, 0.f, 0.f, 0.f};
        bf16x8 bqr = ldfrag(lds, addrQ(0, 16 * wt + lr, 8 * lg));
        bf16x8 bqi = ldfrag(lds, addrQ(1, 16 * wt + lr, 8 * lg));
        #pragma unroll
        for (int ct = 0; ct < 4; ++ct) {
            bf16x8 akr = ldfrag(lds, addrK(0, ct * 16 + lr, 8 * lg));
            bf16x8 aki = ldfrag(lds, addrK(1, ct * 16 + lr, 8 * lg));
            pr[ct] = __builtin_amdgcn_mfma_f32_16x16x32_bf16(akr, bqr, zero, 0, 0, 0);
            pr[ct] = __builtin_amdgcn_mfma_f32_16x16x32_bf16(fneg(aki), bqi, pr[ct], 0, 0, 0);
            pi[ct] = __builtin_amdgcn_mfma_f32_16x16x32_bf16(akr, bqi, zero, 0, 0, 0);
            pi[ct] = __builtin_amdgcn_mfma_f32_16x16x32_bf16(aki, bqr, pi[ct], 0, 0, 0);
        }
        float mr = -1e30f, mi = -1e30f;
        #pragma unroll
        for (int ct = 0; ct < 4; ++ct)
            #pragma unroll
            for (int r = 0; r < 4; ++r) { mr = fmaxf(mr, pr[ct][r]); mi = fmaxf(mi, pi[ct][r]); }
        mr = fmaxf(mr, __shfl_xor(mr, 16)); mr = fmaxf(mr, __shfl_xor(mr, 32));
        mi = fmaxf(mi, __shfl_xor(mi, 16)); mi = fmaxf(mi, __shfl_xor(mi, 32));
        float sr = 0.f, si = 0.f;
        #pragma unroll
        for (int ct = 0; ct < 4; ++ct)
            #pragma unroll
            for (int r = 0; r < 4; ++r) {
                float er = __expf(pr[ct][r] - mr); pr[ct][r] = er; sr += er;
                float ei = __expf(pi[ct][r] - mi); pi[ct][r] = ei; si += ei;
            }
        sr += __shfl_xor(sr, 16); sr += __shfl_xor(sr, 32);
        si += __shfl_xor(si, 16); si += __shfl_xor(si, 32);
        inv_r = 1.f / sr; inv_i = 1.f / si;
    }

    // W A-frags in-register: element (ks, j) <- slot(ct = 2*ks + (j>>2), r = j&3)  (tau)
    bf16x8 awr[2], awi[2], awin[2];
    #pragma unroll
    for (int ks = 0; ks < 2; ++ks) {
        #pragma unroll
        for (int j = 0; j < 8; ++j) {
            const int ct = 2 * ks + (j >> 2), r = j & 3;
            awr[ks][j] = (__bf16)(pr[ct][r] * inv_r);
            awi[ks][j] = (__bf16)(pi[ct][r] * inv_i);
        }
        awin[ks] = fneg(awi[ks]);
    }

    // ============ Phase C: U[e][t] = sum_c W[c][e] X[c][t] (complex); pair splits t ========
    const int nth = (w >> 2) * 4;     // waves 0-3: nt 0..3, waves 4-7: nt 4..7
    f32x4 uacc_r[4], uacc_i[4];
    #pragma unroll
    for (int nt2 = 0; nt2 < 4; ++nt2) {
        const int nt = nth + nt2;
        f32x4 ur = {0.f, 0.f, 0.f, 0.f}, ui = {0.f, 0.f, 0.f, 0.f};
        #pragma unroll
        for (int ks = 0; ks < 2; ++ks) {
            bf16x8 bxr = ldfrag(lds, addrXT(nt * 16 + lr, ks * 32 + 8 * lg));
            bf16x8 bxi = ldfrag(lds, addrXT(nt * 16 + lr, 64 + ks * 32 + 8 * lg));
            ur = __builtin_amdgcn_mfma_f32_16x16x32_bf16(awr[ks], bxr, ur, 0, 0, 0);
            ur = __builtin_amdgcn_mfma_f32_16x16x32_bf16(awin[ks], bxi, ur, 0, 0, 0);
            ui = __builtin_amdgcn_mfma_f32_16x16x32_bf16(awi[ks], bxr, ui, 0, 0, 0);
            ui = __builtin_amdgcn_mfma_f32_16x16x32_bf16(awr[ks], bxi, ui, 0, 0, 0);
        }
        uacc_r[nt2] = ur; uacc_i[nt2] = ui;
    }
    __syncthreads();   // barrier 2: all waves done reading XT -> alias XT region with UT
    #pragma unroll
    for (int nt2 = 0; nt2 < 4; ++nt2) {
        const int s = (nth + nt2) * 16 + lr;
        #pragma unroll
        for (int r = 0; r < 4; ++r) {
            const int e = 16 * wt + 4 * lg + r;
            lds[addrU(0, e, s)] = b16(uacc_r[nt2][r]);
            lds[addrU(1, e, s)] = b16(uacc_i[nt2][r]);
        }
    }
    __syncthreads();   // barrier 3: UT ready

    // ============ Phase D: O[t'][e] = Wv * U (+2bv on imag); wave w -> t'-tile w ============
    {
        const int mt = w;
        bf16x8 av[4];
        #pragma unroll
        for (int ks = 0; ks < 4; ++ks)
            av[ks] = fragWg(Wv + (size_t)(16 * mt + lr) * kT + ks * 32 + 8 * lg);
        const int tp0 = mt * 16 + 4 * lg;
        float bvv[4];
        #pragma unroll
        for (int r = 0; r < 4; ++r) bvv[r] = 2.f * bv[tp0 + r];

        #pragma unroll
        for (int et = 0; et < 4; ++et) {
            f32x4 aor = {0.f, 0.f, 0.f, 0.f}, aoi = {0.f, 0.f, 0.f, 0.f};
            #pragma unroll
            for (int ks = 0; ks < 4; ++ks) {
                bf16x8 bur = ldfrag(lds, addrU(0, et * 16 + lr, ks * 32 + 8 * lg));
                bf16x8 bui = ldfrag(lds, addrU(1, et * 16 + lr, ks * 32 + 8 * lg));
                aor = __builtin_amdgcn_mfma_f32_16x16x32_bf16(av[ks], bur, aor, 0, 0, 0);
                aoi = __builtin_amdgcn_mfma_f32_16x16x32_bf16(av[ks], bui, aoi, 0, 0, 0);
            }
            const int e = et * 16 + lr;
            f32x4 vi;
            #pragma unroll
            for (int r = 0; r < 4; ++r) vi[r] = aoi[r] + bvv[r];
            *(f32x4*)(out + (((size_t)b * kC + e) * kF + f) * kT + tp0)      = aor;
            *(f32x4*)(out + (((size_t)b * kC + 64 + e) * kF + f) * kT + tp0) = vi;
        }
    }
}

extern "C" void kernel_launch(void* const* d_in, const int* in_sizes, int n_in,
                              void* d_out, int out_size, void* d_ws, size_t ws_size,
                              hipStream_t stream) {
    const float* x  = (const float*)d_in[0];
    const float* Wk = (const float*)d_in[1];
    const float* bk = (const float*)d_in[2];
    const float* Wq = (const float*)d_in[3];
    const float* bq = (const float*)d_in[4];
    const float* Wv = (const float*)d_in[5];
    const float* bv = (const float*)d_in[6];
    float* out = (float*)d_out;

    dim3 grid(kF, kB);   // one block per (b, f)
    dim3 block(512);     // 8 waves
    chanattn_mfma5<<<grid, block, 0, stream>>>(x, Wk, bk, Wq, bq, Wv, bv, out);
}